// Round 4
// baseline (273.088 us; speedup 1.0000x reference)
//
#include <hip/hip_runtime.h>
#include <math.h>

// IDMRFLoss on MI355X — R15: eliminate sim materialization (430 MB of HBM
// traffic: 143.6 write + 2x143.6 read) via 3-pass GEMM recompute. The GEMM
// is only 38.7 GFLOP (~16us MFMA floor) so recomputing beats re-reading.
//   A: gemm -> colmax partials (cmPart, 4.5 MB)
//   B: gemm -> exp2 epilogue -> atomicAdd colsum (L2-resident)
//   C: gemm -> rowmax epilogue (folds -log2(colsum)) -> rmPart (2.1 MB)
//   rmreduce: rmPart -> exp2 -> acc
// All passes share the R14 K-loop (3-buf LDS, 2-deep prefetch, counted
// vmcnt) -> acc bits identical across passes; every pass rounds acc
// through bf16 before use, matching the old sim semantics exactly.
// stats/apply/colmax_reduce/finalize unchanged from R14 (228.1us measured).
//
// Layer 0 (relu3_2): B=4, C=256, S=4096, weight 1.0
// Layer 1 (relu4_2): B=4, C=512, S=1024, weight 2.0 (style + content)
//
// Swizzled operand layout (per batch, matrix [S][K] bf16):
//   elem(row,k) at ((row>>4)*(K/8) + (k>>3))*128 + (row&15)*8 + (k&7)
// acc mapping: p = by*128 + wm + t*16 + quad*4 + r ; q = bx*128 + wn + u*16 + lm
//
// Math (per combo): c1 = 1/((1-colmax)/2+eps); log2 domain c1L=c1*log2e,
// c0L=(2-c1)*log2e; colsum_q = sum_p 2^(c0L+c1L*v);
// kmax_p = 2^(max_q (c0L - log2(colsum_q) + c1L*v)); loss = sum -w*log(mean kmax).

#define MRF_EPS 1e-5f
#define LOG2E 1.44269504088896340736f

typedef __attribute__((ext_vector_type(8))) short bf16x8;
typedef __attribute__((ext_vector_type(4))) float f32x4;
typedef unsigned short ushort_t;
struct __align__(8) ushort4_t { ushort_t x, y, z, w; };
struct __align__(16) ushort8_t { ushort_t v[8]; };

__device__ __forceinline__ ushort_t f2bf(float x) {
    unsigned u = __float_as_uint(x);
    u += 0x7FFFu + ((u >> 16) & 1u);
    return (ushort_t)(u >> 16);
}
__device__ __forceinline__ float bf2f(ushort_t u) {
    return __uint_as_float(((unsigned)u) << 16);
}
__device__ __forceinline__ float rndbf(float x) { return bf2f(f2bf(x)); }

// async global->LDS, 16B per lane. LDS dest is wave-uniform base + lane*16.
typedef __attribute__((address_space(1))) const unsigned int gu32;
typedef __attribute__((address_space(3))) unsigned int lu32;
__device__ __forceinline__ void gload16(const ushort_t* g, ushort_t* l) {
    __builtin_amdgcn_global_load_lds((gu32*)(uintptr_t)g, (lu32*)(uintptr_t)l,
                                     16, 0, 0);
}

// ================= stats =================
__global__ __launch_bounds__(256) void stats_all(
    const float* __restrict__ gen3, const float* __restrict__ tar3,
    const float* __restrict__ gen4, const float* __restrict__ tar4,
    float* __restrict__ mean3, float* __restrict__ rg3, float* __restrict__ rt3,
    float* __restrict__ mean4, float* __restrict__ rg4, float* __restrict__ rt4) {
    const float *gen, *tar; float *mean, *rg, *rt; int C, S, b, bx;
    int bid = blockIdx.x;
    if (bid < 256) {            // layer4 first (heavier per block)
        C = 512; S = 1024; b = bid >> 6; bx = bid & 63;
        gen = gen4; tar = tar4; mean = mean4; rg = rg4; rt = rt4;
    } else {
        bid -= 256;
        C = 256; S = 4096; b = bid >> 8; bx = bid & 255;
        gen = gen3; tar = tar3; mean = mean3; rg = rg3; rt = rt3;
    }
    int tid = threadIdx.x, pq = tid & 3, cs = tid >> 2;
    int s0 = bx * 16 + pq * 4;
    const float* g = gen + (size_t)b * C * S + s0;
    const float* t = tar + (size_t)b * C * S + s0;

    f32x4 st = {0.f, 0.f, 0.f, 0.f}, st2 = st, sg = st, sg2 = st;
    for (int c = cs; c < C; c += 64) {
        f32x4 tv = *(const f32x4*)(t + (size_t)c * S);
        f32x4 gv = *(const f32x4*)(g + (size_t)c * S);
        st += tv; st2 += tv * tv; sg += gv; sg2 += gv * gv;
    }
    __shared__ f32x4 red[4][4][64];
    __shared__ f32x4 red2[4][4][4];
    red[0][pq][cs] = st; red[1][pq][cs] = st2; red[2][pq][cs] = sg; red[3][pq][cs] = sg2;
    __syncthreads();
    if (tid < 64) {
        int s_ = tid >> 4, p_ = (tid >> 2) & 3, part = tid & 3;
        f32x4 s = red[s_][p_][part * 16];
#pragma unroll
        for (int j = 1; j < 16; j++) s += red[s_][p_][part * 16 + j];
        red2[s_][p_][part] = s;
    }
    __syncthreads();
    if (tid < 4) {
        f32x4 sts = red2[0][tid][0] + red2[0][tid][1] + red2[0][tid][2] + red2[0][tid][3];
        f32x4 st2s = red2[1][tid][0] + red2[1][tid][1] + red2[1][tid][2] + red2[1][tid][3];
        f32x4 sgs = red2[2][tid][0] + red2[2][tid][1] + red2[2][tid][2] + red2[2][tid][3];
        f32x4 sg2s = red2[3][tid][0] + red2[3][tid][1] + red2[3][tid][2] + red2[3][tid][3];
        f32x4 m, vrt, vrg;
        float invC = 1.f / (float)C;
#pragma unroll
        for (int e = 0; e < 4; e++) {
            float mm = sts[e] * invC;
            m[e] = mm;
            vrt[e] = rsqrtf(st2s[e] - mm * sts[e]);
            vrg[e] = rsqrtf(sg2s[e] - 2.f * mm * sgs[e] + mm * sts[e]);
        }
        int idx = b * S + bx * 16 + tid * 4;
        *(f32x4*)(mean + idx) = m;
        *(f32x4*)(rt + idx) = vrt;
        *(f32x4*)(rg + idx) = vrg;
    }
}

// ================= apply =================
__global__ __launch_bounds__(256) void apply_all(
    const float* __restrict__ gen3, const float* __restrict__ tar3,
    const float* __restrict__ gen4, const float* __restrict__ tar4,
    const float* __restrict__ mean3, const float* __restrict__ rg3, const float* __restrict__ rt3,
    const float* __restrict__ mean4, const float* __restrict__ rg4, const float* __restrict__ rt4,
    ushort_t* __restrict__ gnT3, ushort_t* __restrict__ tnT3,
    ushort_t* __restrict__ gnT4, ushort_t* __restrict__ tnT4) {
    const float *gen, *tar, *mean, *rg, *rt; ushort_t *gnT, *tnT;
    int C, S, b, sxb, cyb;
    int bid = blockIdx.x;
    if (bid < 512) {            // layer4: 4 z * (16 x 8)
        C = 512; S = 1024; b = bid >> 7; int rem = bid & 127;
        cyb = rem >> 4; sxb = rem & 15;
        gen = gen4; tar = tar4; mean = mean4; rg = rg4; rt = rt4; gnT = gnT4; tnT = tnT4;
    } else {                    // layer3: 4 z * (64 x 4)
        bid -= 512;
        C = 256; S = 4096; b = bid >> 8; int rem = bid & 255;
        cyb = rem >> 6; sxb = rem & 63;
        gen = gen3; tar = tar3; mean = mean3; rg = rg3; rt = rt3; gnT = gnT3; tnT = tnT3;
    }
    int tid = threadIdx.x;
    int s0 = sxb * 64, c0 = cyb * 64;
    const float* g = gen + (size_t)b * C * S;
    const float* t = tar + (size_t)b * C * S;
    int tx = tid & 63, tw = tid >> 6;
    int sidx = b * S + s0 + tx;
    float m = mean[sidx], rgv = rg[sidx], rtv = rt[sidx];

    __shared__ ushort_t tg[64][72], tt_[64][72];
#pragma unroll
    for (int i = 0; i < 16; i++) {
        int cl = tw * 16 + i;
        float gv = g[(size_t)(c0 + cl) * S + s0 + tx];
        float tv = t[(size_t)(c0 + cl) * S + s0 + tx];
        tg[tx][cl] = f2bf((gv - m) * rgv);
        tt_[tx][cl] = f2bf((tv - m) * rtv);
    }
    __syncthreads();
    int KC = C >> 3;
#pragma unroll
    for (int j = 0; j < 2; j++) {
        int p = j * 256 + tid;
        int s = p & 63, ch = p >> 6;
        int row = s0 + s;
        int r16 = row >> 4, lm = row & 15;
        size_t off = (size_t)b * S * C + (((size_t)r16 * KC + (c0 >> 3) + ch) * 16 + lm) * 8;
        *(ushort8_t*)(gnT + off) = *(const ushort8_t*)&tg[s][ch * 8];
        *(ushort8_t*)(tnT + off) = *(const ushort8_t*)&tt_[s][ch * 8];
    }
}

// ===== shared GEMM core (R14 K-loop: 3-buf LDS, 2-deep, counted vmcnt) =====
template <int K>
__device__ __forceinline__ void gemm_core(
    const ushort_t* __restrict__ A, const ushort_t* __restrict__ B,
    int bx, int by, ushort_t* __restrict__ lds, f32x4 (&acc)[4][4]) {
    const int tid = threadIdx.x;
    const int lane = tid & 63, wave = tid >> 6;
    const int wm = (wave & 1) * 64, wn = (wave >> 1) * 64;
    const int lm = lane & 15, quad = lane >> 4;

    constexpr int KC = K / 8;
    constexpr int KB = K / 32;

    const ushort_t* segsrc[4];
    ushort_t* segdst[4];
#pragma unroll
    for (int i = 0; i < 4; i++) {
        int s = wave * 4 + i;
        segsrc[i] = (s < 8)
            ? A + ((size_t)(by * 8 + s) * KC) * 128 + lane * 8
            : B + ((size_t)(bx * 8 + (s - 8)) * KC) * 128 + lane * 8;
        segdst[i] = lds + s * 512;
    }

    auto stage = [&](int buf, int kb) {
#pragma unroll
        for (int i = 0; i < 4; i++)
            gload16(segsrc[i] + (size_t)kb * 512, segdst[i] + buf * 8192);
    };

#pragma unroll
    for (int t = 0; t < 4; t++)
#pragma unroll
        for (int u = 0; u < 4; u++) acc[t][u] = (f32x4){0.f, 0.f, 0.f, 0.f};

    stage(0, 0);
    stage(1, 1);
    asm volatile("s_waitcnt vmcnt(4)" ::: "memory");
    __builtin_amdgcn_s_barrier();

    const ushort_t* lA = lds + (wm >> 4) * 512 + quad * 128 + lm * 8;
    const ushort_t* lB = lds + 4096 + (wn >> 4) * 512 + quad * 128 + lm * 8;

#pragma unroll
    for (int kb = 0; kb < KB; kb++) {
        const int cur = (kb % 3) * 8192;
        if (kb + 2 < KB) stage((kb + 2) % 3, kb + 2);
        bf16x8 a[4], b[4];
#pragma unroll
        for (int t = 0; t < 4; t++) {
            a[t] = *(const bf16x8*)(lA + cur + t * 512);
            b[t] = *(const bf16x8*)(lB + cur + t * 512);
        }
        asm volatile("s_waitcnt lgkmcnt(0)" ::: "memory");
        __builtin_amdgcn_sched_barrier(0);
#pragma unroll
        for (int t = 0; t < 4; t++)
#pragma unroll
            for (int u = 0; u < 4; u++)
                acc[t][u] = __builtin_amdgcn_mfma_f32_16x16x32_bf16(a[t], b[u], acc[t][u], 0, 0, 0);
        if (kb + 1 < KB) {
            if (kb + 2 < KB) asm volatile("s_waitcnt vmcnt(4)" ::: "memory");
            else             asm volatile("s_waitcnt vmcnt(0)" ::: "memory");
            __builtin_amdgcn_s_barrier();
        }
    }
}

// ===== pass A: colmax partials (identical numerics to R14 epilogue) =====
__device__ __forceinline__ void epilogueA(
    f32x4 (&acc)[4][4], float* __restrict__ cmPart, int S, int bx, int by) {
    int tid = threadIdx.x, lane = tid & 63, wave = tid >> 6;
    int wn = (wave >> 1) * 64;
    int q0 = bx * 128;
    float cmax[4] = {-INFINITY, -INFINITY, -INFINITY, -INFINITY};
#pragma unroll
    for (int t = 0; t < 4; t++)
#pragma unroll
        for (int u = 0; u < 4; u++) {
            f32x4 v = acc[t][u];
            float mx = fmaxf(fmaxf(rndbf(v.x), rndbf(v.y)), fmaxf(rndbf(v.z), rndbf(v.w)));
            cmax[u] = fmaxf(cmax[u], mx);
        }
    int r = by * 2 + (wave & 1);
#pragma unroll
    for (int u = 0; u < 4; u++) {
        float m = cmax[u];
        m = fmaxf(m, __shfl_xor(m, 16, 64));
        m = fmaxf(m, __shfl_xor(m, 32, 64));
        if (lane < 16) cmPart[(size_t)r * S + q0 + wn + u * 16 + lane] = m;
    }
}

__global__ __launch_bounds__(256) void gemmA_all(
    const ushort_t* __restrict__ tnT3, const ushort_t* __restrict__ gnT3,
    float* __restrict__ cmPart3,
    const ushort_t* __restrict__ tnT4, const ushort_t* __restrict__ gnT4,
    float* __restrict__ cmPart4) {
    __shared__ ushort_t lds[24576];
    f32x4 acc[4][4];
    int bid = blockIdx.x;
    if (bid < 256) {
        int z = bid >> 6, rem = bid & 63, by = rem >> 3, bx = rem & 7;
        gemm_core<512>(tnT4 + (size_t)z * 524288, gnT4 + (size_t)z * 524288, bx, by, lds, acc);
        epilogueA(acc, cmPart4 + (size_t)z * 16384, 1024, bx, by);
    } else {
        bid -= 256;
        int z = bid >> 10, rem = bid & 1023, by = rem >> 5, bx = rem & 31;
        gemm_core<256>(tnT3 + (size_t)z * 1048576, gnT3 + (size_t)z * 1048576, bx, by, lds, acc);
        epilogueA(acc, cmPart3 + (size_t)z * 262144, 4096, bx, by);
    }
}

// ================= colmax reduce -> coef, zero colsum + acc =================
__global__ __launch_bounds__(256) void colmax_reduce_all(
    const float* __restrict__ cmPart3, float2* __restrict__ coef3, float* __restrict__ colsum3,
    const float* __restrict__ cmPart4, float2* __restrict__ coef4, float* __restrict__ colsum4,
    float* __restrict__ acc) {
    const float* cmPart; float2* coef; float* colsum; int S, R, qb, accIdx;
    int bid = blockIdx.x;
    if (bid < 16) {             // layer4: 4 z * 4 blocks
        int z = bid >> 2; qb = bid & 3; S = 1024; R = 16; accIdx = 4 + z;
        cmPart = cmPart4 + (size_t)z * 16384; coef = coef4 + (size_t)z * 1024;
        colsum = colsum4 + (size_t)z * 1024;
    } else {
        bid -= 16;
        int z = bid >> 4; qb = bid & 15; S = 4096; R = 64; accIdx = z;
        cmPart = cmPart3 + (size_t)z * 262144; coef = coef3 + (size_t)z * 4096;
        colsum = colsum3 + (size_t)z * 4096;
    }
    if (qb == 0 && threadIdx.x == 0) acc[accIdx] = 0.f;
    int q = qb * 256 + threadIdx.x;
    float m = cmPart[q];
    for (int r = 1; r < R; r++) m = fmaxf(m, cmPart[(size_t)r * S + q]);
    float c1 = 1.f / ((1.f - m) * 0.5f + MRF_EPS);
    coef[q] = make_float2((2.f - c1) * LOG2E, c1 * LOG2E);
    colsum[q] = 0.f;
}

// ===== pass B: colsum via recompute + exp2 epilogue =====
__device__ __forceinline__ void epilogueB(
    f32x4 (&acc)[4][4], const float2* __restrict__ coef,
    float* __restrict__ colsum, int bx) {
    int tid = threadIdx.x, lane = tid & 63, wave = tid >> 6;
    int wn = (wave >> 1) * 64, lm = lane & 15;
    int qb = bx * 128 + wn + lm;
    float c0[4], c1[4], su[4];
#pragma unroll
    for (int u = 0; u < 4; u++) {
        float2 cc = coef[qb + u * 16];
        c0[u] = cc.x; c1[u] = cc.y; su[u] = 0.f;
    }
#pragma unroll
    for (int t = 0; t < 4; t++)
#pragma unroll
        for (int u = 0; u < 4; u++) {
            f32x4 v = acc[t][u];
            su[u] += exp2f(c0[u] + c1[u] * rndbf(v.x));
            su[u] += exp2f(c0[u] + c1[u] * rndbf(v.y));
            su[u] += exp2f(c0[u] + c1[u] * rndbf(v.z));
            su[u] += exp2f(c0[u] + c1[u] * rndbf(v.w));
        }
#pragma unroll
    for (int u = 0; u < 4; u++) {
        su[u] += __shfl_xor(su[u], 16, 64);
        su[u] += __shfl_xor(su[u], 32, 64);
        if (lane < 16) atomicAdd(colsum + qb + u * 16, su[u]);
    }
}

__global__ __launch_bounds__(256) void gemmB_all(
    const ushort_t* __restrict__ tnT3, const ushort_t* __restrict__ gnT3,
    const float2* __restrict__ coef3, float* __restrict__ colsum3,
    const ushort_t* __restrict__ tnT4, const ushort_t* __restrict__ gnT4,
    const float2* __restrict__ coef4, float* __restrict__ colsum4) {
    __shared__ ushort_t lds[24576];
    f32x4 acc[4][4];
    int bid = blockIdx.x;
    if (bid < 256) {
        int z = bid >> 6, rem = bid & 63, by = rem >> 3, bx = rem & 7;
        gemm_core<512>(tnT4 + (size_t)z * 524288, gnT4 + (size_t)z * 524288, bx, by, lds, acc);
        epilogueB(acc, coef4 + (size_t)z * 1024, colsum4 + (size_t)z * 1024, bx);
    } else {
        bid -= 256;
        int z = bid >> 10, rem = bid & 1023, by = rem >> 5, bx = rem & 31;
        gemm_core<256>(tnT3 + (size_t)z * 1048576, gnT3 + (size_t)z * 1048576, bx, by, lds, acc);
        epilogueB(acc, coef3 + (size_t)z * 4096, colsum3 + (size_t)z * 4096, bx);
    }
}

// ===== pass C: rowmax partials via recompute (folds -log2(colsum)) =====
__device__ __forceinline__ void epilogueC(
    f32x4 (&acc)[4][4], const float2* __restrict__ coef,
    const float* __restrict__ colsum, float* __restrict__ rmPart,
    int S, int bx, int by, float* __restrict__ rowm /* 256 floats, aliases lds */) {
    int tid = threadIdx.x, lane = tid & 63, wave = tid >> 6;
    int wm = (wave & 1) * 64, wn = (wave >> 1) * 64;
    int lm = lane & 15, quad = lane >> 4;
    int qb = bx * 128 + wn + lm;
    float c0p[4], c1[4];
#pragma unroll
    for (int u = 0; u < 4; u++) {
        float2 cc = coef[qb + u * 16];
        c0p[u] = cc.x - log2f(colsum[qb + u * 16]);
        c1[u] = cc.y;
    }
    float m[4][4];
#pragma unroll
    for (int t = 0; t < 4; t++)
#pragma unroll
        for (int r = 0; r < 4; r++) m[t][r] = -INFINITY;
#pragma unroll
    for (int t = 0; t < 4; t++)
#pragma unroll
        for (int u = 0; u < 4; u++) {
            f32x4 v = acc[t][u];
            m[t][0] = fmaxf(m[t][0], c0p[u] + c1[u] * rndbf(v.x));
            m[t][1] = fmaxf(m[t][1], c0p[u] + c1[u] * rndbf(v.y));
            m[t][2] = fmaxf(m[t][2], c0p[u] + c1[u] * rndbf(v.z));
            m[t][3] = fmaxf(m[t][3], c0p[u] + c1[u] * rndbf(v.w));
        }
    // reduce across the 16 lm lanes (columns) — xor 1,2,4,8
#pragma unroll
    for (int off = 1; off <= 8; off <<= 1)
#pragma unroll
        for (int t = 0; t < 4; t++)
#pragma unroll
            for (int r = 0; r < 4; r++)
                m[t][r] = fmaxf(m[t][r], __shfl_xor(m[t][r], off, 64));
    // combine the two wn halves via LDS (reuses staging LDS — barrier first;
    // barrier counts stay uniform: every wave exits the K-loop with the same
    // barrier count, so these s_barriers pair correctly).
    __syncthreads();
    if (lm == 0) {
#pragma unroll
        for (int t = 0; t < 4; t++)
#pragma unroll
            for (int r = 0; r < 4; r++)
                rowm[(wave >> 1) * 128 + wm + t * 16 + quad * 4 + r] = m[t][r];
    }
    __syncthreads();
    if (tid < 128) {
        float v = fmaxf(rowm[tid], rowm[128 + tid]);
        rmPart[(size_t)bx * S + by * 128 + tid] = v;
    }
}

__global__ __launch_bounds__(256) void gemmC_all(
    const ushort_t* __restrict__ tnT3, const ushort_t* __restrict__ gnT3,
    const float2* __restrict__ coef3, const float* __restrict__ colsum3,
    float* __restrict__ rmPart3,
    const ushort_t* __restrict__ tnT4, const ushort_t* __restrict__ gnT4,
    const float2* __restrict__ coef4, const float* __restrict__ colsum4,
    float* __restrict__ rmPart4) {
    __shared__ ushort_t lds[24576];
    f32x4 acc[4][4];
    int bid = blockIdx.x;
    if (bid < 256) {
        int z = bid >> 6, rem = bid & 63, by = rem >> 3, bx = rem & 7;
        gemm_core<512>(tnT4 + (size_t)z * 524288, gnT4 + (size_t)z * 524288, bx, by, lds, acc);
        epilogueC(acc, coef4 + (size_t)z * 1024, colsum4 + (size_t)z * 1024,
                  rmPart4 + (size_t)z * 8192, 1024, bx, by, (float*)lds);
    } else {
        bid -= 256;
        int z = bid >> 10, rem = bid & 1023, by = rem >> 5, bx = rem & 31;
        gemm_core<256>(tnT3 + (size_t)z * 1048576, gnT3 + (size_t)z * 1048576, bx, by, lds, acc);
        epilogueC(acc, coef3 + (size_t)z * 4096, colsum3 + (size_t)z * 4096,
                  rmPart3 + (size_t)z * 131072, 4096, bx, by, (float*)lds);
    }
}

// ===== rowmax partial reduce -> exp2 -> acc =====
__global__ __launch_bounds__(256) void rmreduce_all(
    const float* __restrict__ rmPart3, const float* __restrict__ rmPart4,
    float* __restrict__ acc) {
    const float* rm; int S, nQB, p; float* slot;
    int bid = blockIdx.x;
    if (bid < 64) {             // layer3: 4 z * 16 blocks
        int z = bid >> 4, blk = bid & 15; S = 4096; nQB = 32;
        rm = rmPart3 + (size_t)z * 131072;
        p = blk * 256 + threadIdx.x; slot = acc + z;
    } else {
        bid -= 64;              // layer4: 4 z * 4 blocks
        int z = bid >> 2, blk = bid & 3; S = 1024; nQB = 8;
        rm = rmPart4 + (size_t)z * 8192;
        p = blk * 256 + threadIdx.x; slot = acc + 4 + z;
    }
    float m = rm[p];
    for (int bx = 1; bx < nQB; bx++) m = fmaxf(m, rm[(size_t)bx * S + p]);
    float k = exp2f(m);
#pragma unroll
    for (int off = 32; off >= 1; off >>= 1) k += __shfl_xor(k, off, 64);
    __shared__ float part[4];
    if ((threadIdx.x & 63) == 0) part[threadIdx.x >> 6] = k;
    __syncthreads();
    if (threadIdx.x == 0)
        atomicAdd(slot, part[0] + part[1] + part[2] + part[3]);
}

__global__ void finalize_kernel(const float* __restrict__ acc, float* __restrict__ out) {
    float loss = 0.f;
    for (int b = 0; b < 4; b++) loss += -logf(acc[b] * (1.f / 4096.f));
    for (int b = 0; b < 4; b++) loss += -2.f * logf(acc[4 + b] * (1.f / 1024.f));
    out[0] = loss;
}

extern "C" void kernel_launch(void* const* d_in, const int* in_sizes, int n_in,
                              void* d_out, int out_size, void* d_ws, size_t ws_size,
                              hipStream_t stream) {
    const float* gen3 = (const float*)d_in[0];
    const float* tar3 = (const float*)d_in[1];
    const float* gen4 = (const float*)d_in[2];
    const float* tar4 = (const float*)d_in[3];

    char* wsb = (char*)d_ws;
    size_t off = 0;
    auto alloc = [&](size_t bytes) {
        void* p = wsb + off;
        off += (bytes + 255) & ~(size_t)255;
        return p;
    };
    // layer3 (z=4): S=4096, C=256, R=64, nQB=32
    ushort_t* gnT3 = (ushort_t*)alloc((size_t)4 * 1048576 * 2);    // 8.4 MB
    ushort_t* tnT3 = (ushort_t*)alloc((size_t)4 * 1048576 * 2);    // 8.4 MB
    float* cmPart3 = (float*)alloc((size_t)4 * 262144 * 4);        // 4.2 MB
    float2* coef3 = (float2*)alloc((size_t)4 * 4096 * 8);
    float* colsum3 = (float*)alloc((size_t)4 * 4096 * 4);
    float* rmPart3 = (float*)alloc((size_t)4 * 131072 * 4);        // 2.1 MB
    float* mean3 = (float*)alloc((size_t)4 * 4096 * 4);
    float* rg3 = (float*)alloc((size_t)4 * 4096 * 4);
    float* rt3 = (float*)alloc((size_t)4 * 4096 * 4);
    // layer4 (z=4): S=1024, C=512, R=16, nQB=8
    ushort_t* gnT4 = (ushort_t*)alloc((size_t)4 * 524288 * 2);     // 4.2 MB
    ushort_t* tnT4 = (ushort_t*)alloc((size_t)4 * 524288 * 2);     // 4.2 MB
    float* cmPart4 = (float*)alloc((size_t)4 * 16384 * 4);
    float2* coef4 = (float2*)alloc((size_t)4 * 1024 * 8);
    float* colsum4 = (float*)alloc((size_t)4 * 1024 * 4);
    float* rmPart4 = (float*)alloc((size_t)4 * 8192 * 4);
    float* mean4 = (float*)alloc((size_t)4 * 1024 * 4);
    float* rg4 = (float*)alloc((size_t)4 * 1024 * 4);
    float* rt4 = (float*)alloc((size_t)4 * 1024 * 4);
    float* acc = (float*)alloc(64 * 4);
    // total ~35 MB (no sim materialization)

    stats_all<<<256 + 1024, 256, 0, stream>>>(
        gen3, tar3, gen4, tar4, mean3, rg3, rt3, mean4, rg4, rt4);
    apply_all<<<512 + 1024, 256, 0, stream>>>(
        gen3, tar3, gen4, tar4, mean3, rg3, rt3, mean4, rg4, rt4,
        gnT3, tnT3, gnT4, tnT4);
    gemmA_all<<<256 + 4096, 256, 0, stream>>>(
        tnT3, gnT3, cmPart3, tnT4, gnT4, cmPart4);
    colmax_reduce_all<<<16 + 64, 256, 0, stream>>>(
        cmPart3, coef3, colsum3, cmPart4, coef4, colsum4, acc);
    gemmB_all<<<256 + 4096, 256, 0, stream>>>(
        tnT3, gnT3, coef3, colsum3, tnT4, gnT4, coef4, colsum4);
    gemmC_all<<<256 + 4096, 256, 0, stream>>>(
        tnT3, gnT3, coef3, colsum3, rmPart3, tnT4, gnT4, coef4, colsum4, rmPart4);
    rmreduce_all<<<64 + 16, 256, 0, stream>>>(rmPart3, rmPart4, acc);
    finalize_kernel<<<1, 1, 0, stream>>>(acc, (float*)d_out);
}

// Round 5
// 219.083 us; speedup vs baseline: 1.2465x; 1.2465x over previous
//
#include <hip/hip_runtime.h>
#include <math.h>

// IDMRFLoss on MI355X — R16: back to R14 structure (R15's 3-pass recompute
// regressed: a gemm pass costs ~51-56us regardless of the sim write, so
// recompute > re-read). Two changes on the R14 base (228.1us):
//  1. gemm core: remove the forced lgkmcnt(0) drain before the MFMA cluster
//     (plain C++ ds_reads are compiler-visible; the drain serialized ~96cyc
//     of LDS reads onto every MFMA phase). sched_barrier(0) moved to after
//     each s_barrier (blocks hoisting reads above buffer-ready). s_setprio
//     around MFMA cluster (T5).
//  2. stats_all + apply_all fused into prep_all: one pass over the 50.4 MB
//     inputs (was two), data held in registers, stats accumulation order
//     copied verbatim (bit-identical), LDS transpose, swizzled writes.
//
// Layer 0 (relu3_2): B=4, C=256, S=4096, weight 1.0
// Layer 1 (relu4_2): B=4, C=512, S=1024, weight 2.0 (style + content)
//
// Swizzled operand layout (per batch, matrix [S][K] bf16):
//   elem(row,k) at ((row>>4)*(K/8) + (k>>3))*128 + (row&15)*8 + (k&7)
// sim blocked bf16 layout (per 128x128 block at (by,bx)):
//   elem = (by*nQB+bx)*16384 + slot*4096 + (t*4+u)*256 + quad*64 + lm*4 + r
//   p = by*128+(slot&1)*64+t*16+quad*4+r ; q = bx*128+(slot>>1)*64+u*16+lm
//
// Math (per combo): c1 = 1/((1-colmax)/2+eps); log2 domain c1L=c1*log2e,
// c0L=(2-c1)*log2e; colsum_q = sum_p 2^(c0L+c1L*v);
// kmax_p = 2^(max_q (c0L - log2(colsum_q) + c1L*v)); loss = sum -w*log(mean kmax).

#define MRF_EPS 1e-5f
#define LOG2E 1.44269504088896340736f

typedef __attribute__((ext_vector_type(8))) short bf16x8;
typedef __attribute__((ext_vector_type(4))) float f32x4;
typedef unsigned short ushort_t;
struct __align__(8) ushort4_t { ushort_t x, y, z, w; };
struct __align__(16) ushort8_t { ushort_t v[8]; };

__device__ __forceinline__ ushort_t f2bf(float x) {
    unsigned u = __float_as_uint(x);
    u += 0x7FFFu + ((u >> 16) & 1u);
    return (ushort_t)(u >> 16);
}
__device__ __forceinline__ float bf2f(ushort_t u) {
    return __uint_as_float(((unsigned)u) << 16);
}

// async global->LDS, 16B per lane. LDS dest is wave-uniform base + lane*16.
typedef __attribute__((address_space(1))) const unsigned int gu32;
typedef __attribute__((address_space(3))) unsigned int lu32;
__device__ __forceinline__ void gload16(const ushort_t* g, ushort_t* l) {
    __builtin_amdgcn_global_load_lds((gu32*)(uintptr_t)g, (lu32*)(uintptr_t)l,
                                     16, 0, 0);
}

// ===== prep: fused stats+apply (one input pass, data held in registers) =====
// One block = 16 spatial rows (one swizzle row16-group) x full C.
// Stats accumulation order is copied verbatim from the old stats_all
// (bit-identical mean/rg/rt), then normalize the register-held values,
// transpose via LDS, write swizzled gnT/tnT exactly as old apply_all.
template <int C>
__device__ __forceinline__ void prep_body(
    const float* __restrict__ gen, const float* __restrict__ tar,
    ushort_t* __restrict__ gnT, ushort_t* __restrict__ tnT,
    int S, int b, int bx, char* __restrict__ smem) {
    constexpr int KN = C / 64;   // f32x4 loads per thread per tensor
    constexpr int KC = C / 8;    // swizzle chunks
    constexpr int CP = C + 8;    // padded LDS tile stride (elems)
    const int tid = threadIdx.x, pq = tid & 3, cs = tid >> 2;
    const int s0 = bx * 16;

    f32x4* red  = (f32x4*)smem;            // [4][4][64], 16 KB (dead after stats)
    f32x4* red2 = (f32x4*)(smem + 16384);  // [4][4][4]
    ushort_t* tileG = (ushort_t*)smem;     // [16][CP] bf16 — aliases red region
    ushort_t* tileT = tileG + 16 * CP;
    float* sm  = (float*)(smem + 33280);   // [16] mean (beyond tile region)
    float* srt = sm + 16;                  // [16] rsqrt var_t
    float* srg = sm + 32;                  // [16] rsqrt var_g

    const float* g = gen + (size_t)b * C * S + s0 + pq * 4;
    const float* t = tar + (size_t)b * C * S + s0 + pq * 4;

    f32x4 gv[KN], tv[KN];
    f32x4 st = {0.f, 0.f, 0.f, 0.f}, st2 = st, sg = st, sg2 = st;
#pragma unroll
    for (int k = 0; k < KN; k++) {          // c = cs + 64k, ascending (== old order)
        tv[k] = *(const f32x4*)(t + (size_t)(cs + 64 * k) * S);
        gv[k] = *(const f32x4*)(g + (size_t)(cs + 64 * k) * S);
        st += tv[k]; st2 += tv[k] * tv[k]; sg += gv[k]; sg2 += gv[k] * gv[k];
    }
    red[(0 * 4 + pq) * 64 + cs] = st;  red[(1 * 4 + pq) * 64 + cs] = st2;
    red[(2 * 4 + pq) * 64 + cs] = sg;  red[(3 * 4 + pq) * 64 + cs] = sg2;
    __syncthreads();
    if (tid < 64) {
        int s_ = tid >> 4, p_ = (tid >> 2) & 3, part = tid & 3;
        f32x4 s = red[(s_ * 4 + p_) * 64 + part * 16];
#pragma unroll
        for (int j = 1; j < 16; j++) s += red[(s_ * 4 + p_) * 64 + part * 16 + j];
        red2[(s_ * 4 + p_) * 4 + part] = s;
    }
    __syncthreads();
    if (tid < 4) {
        f32x4 sts  = red2[(0*4+tid)*4+0] + red2[(0*4+tid)*4+1] + red2[(0*4+tid)*4+2] + red2[(0*4+tid)*4+3];
        f32x4 st2s = red2[(1*4+tid)*4+0] + red2[(1*4+tid)*4+1] + red2[(1*4+tid)*4+2] + red2[(1*4+tid)*4+3];
        f32x4 sgs  = red2[(2*4+tid)*4+0] + red2[(2*4+tid)*4+1] + red2[(2*4+tid)*4+2] + red2[(2*4+tid)*4+3];
        f32x4 sg2s = red2[(3*4+tid)*4+0] + red2[(3*4+tid)*4+1] + red2[(3*4+tid)*4+2] + red2[(3*4+tid)*4+3];
        f32x4 m, vrt, vrg;
        float invC = 1.f / (float)C;
#pragma unroll
        for (int e = 0; e < 4; e++) {
            float mm = sts[e] * invC;
            m[e] = mm;
            vrt[e] = rsqrtf(st2s[e] - mm * sts[e]);
            vrg[e] = rsqrtf(sg2s[e] - 2.f * mm * sgs[e] + mm * sts[e]);
        }
        *(f32x4*)&sm[tid * 4] = m;
        *(f32x4*)&srt[tid * 4] = vrt;
        *(f32x4*)&srg[tid * 4] = vrg;
    }
    __syncthreads();   // red/red2 dead; tile region may now be written
    f32x4 m4  = *(f32x4*)&sm[pq * 4];
    f32x4 rt4 = *(f32x4*)&srt[pq * 4];
    f32x4 rg4 = *(f32x4*)&srg[pq * 4];
#pragma unroll
    for (int k = 0; k < KN; k++) {
        int c = cs + 64 * k;
#pragma unroll
        for (int e = 0; e < 4; e++) {
            tileG[(pq * 4 + e) * CP + c] = f2bf((gv[k][e] - m4[e]) * rg4[e]);
            tileT[(pq * 4 + e) * CP + c] = f2bf((tv[k][e] - m4[e]) * rt4[e]);
        }
    }
    __syncthreads();
    const int lm = tid & 15;
    const int r16 = s0 >> 4;
    size_t obase = (size_t)b * (size_t)S * C;
#pragma unroll
    for (int j = 0; j < KC / 16; j++) {
        int ch = (tid >> 4) + 16 * j;
        size_t off = obase + (((size_t)r16 * KC + ch) * 16 + lm) * 8;
        *(ushort8_t*)(gnT + off) = *(const ushort8_t*)&tileG[lm * CP + ch * 8];
        *(ushort8_t*)(tnT + off) = *(const ushort8_t*)&tileT[lm * CP + ch * 8];
    }
}

__global__ __launch_bounds__(256) void prep_all(
    const float* __restrict__ gen3, const float* __restrict__ tar3,
    const float* __restrict__ gen4, const float* __restrict__ tar4,
    ushort_t* __restrict__ gnT3, ushort_t* __restrict__ tnT3,
    ushort_t* __restrict__ gnT4, ushort_t* __restrict__ tnT4) {
    __shared__ __align__(16) char smem[33536];
    int bid = blockIdx.x;
    if (bid < 256) {            // layer4: 4 z * 64 row-groups
        int z = bid >> 6, bx = bid & 63;
        prep_body<512>(gen4, tar4, gnT4, tnT4, 1024, z, bx, smem);
    } else {                    // layer3: 4 z * 256 row-groups
        bid -= 256;
        int z = bid >> 8, bx = bid & 255;
        prep_body<256>(gen3, tar3, gnT3, tnT3, 4096, z, bx, smem);
    }
}

// ===== gemm (R16 core: 3-buf LDS, 2-deep prefetch, counted vmcnt; NO forced
// lgkm drain — compiler interleaves ds_read waits with MFMA; setprio on MFMA) =====
template <int K>
__device__ __forceinline__ void gemm_body(
    const ushort_t* __restrict__ A, const ushort_t* __restrict__ B,
    ushort_t* __restrict__ sim, float* __restrict__ cmPart,
    int S, int bx, int by, ushort_t* __restrict__ lds) {
    const int tid = threadIdx.x;
    const int lane = tid & 63, wave = tid >> 6;
    const int wm = (wave & 1) * 64, wn = (wave >> 1) * 64;
    const int lm = lane & 15, quad = lane >> 4;
    const int q0 = bx * 128;

    constexpr int KC = K / 8;
    constexpr int KB = K / 32;

    const ushort_t* segsrc[4];
    ushort_t* segdst[4];
#pragma unroll
    for (int i = 0; i < 4; i++) {
        int s = wave * 4 + i;
        segsrc[i] = (s < 8)
            ? A + ((size_t)(by * 8 + s) * KC) * 128 + lane * 8
            : B + ((size_t)(bx * 8 + (s - 8)) * KC) * 128 + lane * 8;
        segdst[i] = lds + s * 512;
    }

    auto stage = [&](int buf, int kb) {
#pragma unroll
        for (int i = 0; i < 4; i++)
            gload16(segsrc[i] + (size_t)kb * 512, segdst[i] + buf * 8192);
    };

    f32x4 acc[4][4];
#pragma unroll
    for (int t = 0; t < 4; t++)
#pragma unroll
        for (int u = 0; u < 4; u++) acc[t][u] = (f32x4){0.f, 0.f, 0.f, 0.f};

    stage(0, 0);
    stage(1, 1);
    asm volatile("s_waitcnt vmcnt(4)" ::: "memory");
    __builtin_amdgcn_s_barrier();
    __builtin_amdgcn_sched_barrier(0);   // nothing crosses the buffer-ready point

    const ushort_t* lA = lds + (wm >> 4) * 512 + quad * 128 + lm * 8;
    const ushort_t* lB = lds + 4096 + (wn >> 4) * 512 + quad * 128 + lm * 8;

#pragma unroll
    for (int kb = 0; kb < KB; kb++) {
        const int cur = (kb % 3) * 8192;
        if (kb + 2 < KB) stage((kb + 2) % 3, kb + 2);
        bf16x8 a[4], b[4];
#pragma unroll
        for (int t = 0; t < 4; t++) {
            a[t] = *(const bf16x8*)(lA + cur + t * 512);
            b[t] = *(const bf16x8*)(lB + cur + t * 512);
        }
        // no forced lgkm drain: compiler emits fine-grained lgkmcnt per MFMA dep
        __builtin_amdgcn_s_setprio(1);
#pragma unroll
        for (int t = 0; t < 4; t++)
#pragma unroll
            for (int u = 0; u < 4; u++)
                acc[t][u] = __builtin_amdgcn_mfma_f32_16x16x32_bf16(a[t], b[u], acc[t][u], 0, 0, 0);
        __builtin_amdgcn_s_setprio(0);
        if (kb + 1 < KB) {
            if (kb + 2 < KB) asm volatile("s_waitcnt vmcnt(4)" ::: "memory");
            else             asm volatile("s_waitcnt vmcnt(0)" ::: "memory");
            __builtin_amdgcn_s_barrier();
            __builtin_amdgcn_sched_barrier(0);
        }
    }

    int nQB = S >> 7;
    size_t base = ((size_t)(by * nQB + bx)) * 16384
                + (size_t)(wave * 4096 + quad * 64 + lm * 4);
    float cmax[4] = {-INFINITY, -INFINITY, -INFINITY, -INFINITY};
#pragma unroll
    for (int t = 0; t < 4; t++)
#pragma unroll
        for (int u = 0; u < 4; u++) {
            f32x4 v = acc[t][u];
            ushort4_t o;
            o.x = f2bf(v.x); o.y = f2bf(v.y); o.z = f2bf(v.z); o.w = f2bf(v.w);
            *(ushort4_t*)(sim + base + (t * 4 + u) * 256) = o;
            float mx = fmaxf(fmaxf(bf2f(o.x), bf2f(o.y)), fmaxf(bf2f(o.z), bf2f(o.w)));
            cmax[u] = fmaxf(cmax[u], mx);
        }
    int r = by * 2 + (wave & 1);
#pragma unroll
    for (int u = 0; u < 4; u++) {
        float m = cmax[u];
        m = fmaxf(m, __shfl_xor(m, 16, 64));
        m = fmaxf(m, __shfl_xor(m, 32, 64));
        if (lane < 16) cmPart[(size_t)r * S + q0 + wn + u * 16 + lane] = m;
    }
}

__global__ __launch_bounds__(256) void gemm_all(
    const ushort_t* __restrict__ tnT3, const ushort_t* __restrict__ gnT3,
    ushort_t* __restrict__ sim3, float* __restrict__ cmPart3,
    const ushort_t* __restrict__ tnT4, const ushort_t* __restrict__ gnT4,
    ushort_t* __restrict__ sim4, float* __restrict__ cmPart4) {
    __shared__ ushort_t lds[24576];   // 3 bufs x (A 8KB + B 8KB) = 48 KB
    int bid = blockIdx.x;
    if (bid < 256) {            // layer4 first (2x K per block)
        int z = bid >> 6, rem = bid & 63, by = rem >> 3, bx = rem & 7;
        gemm_body<512>(tnT4 + (size_t)z * 524288, gnT4 + (size_t)z * 524288,
                       sim4 + (size_t)z * 1048576, cmPart4 + (size_t)z * 16384,
                       1024, bx, by, lds);
    } else {
        bid -= 256;
        int z = bid >> 10, rem = bid & 1023, by = rem >> 5, bx = rem & 31;
        gemm_body<256>(tnT3 + (size_t)z * 1048576, gnT3 + (size_t)z * 1048576,
                       sim3 + (size_t)z * 16777216, cmPart3 + (size_t)z * 262144,
                       4096, bx, by, lds);
    }
}

// ================= colmax reduce -> coef, zero colsum + acc =================
__global__ __launch_bounds__(256) void colmax_reduce_all(
    const float* __restrict__ cmPart3, float2* __restrict__ coef3, float* __restrict__ colsum3,
    const float* __restrict__ cmPart4, float2* __restrict__ coef4, float* __restrict__ colsum4,
    float* __restrict__ acc) {
    const float* cmPart; float2* coef; float* colsum; int S, R, qb, accIdx;
    int bid = blockIdx.x;
    if (bid < 16) {             // layer4: 4 z * 4 blocks
        int z = bid >> 2; qb = bid & 3; S = 1024; R = 16; accIdx = 4 + z;
        cmPart = cmPart4 + (size_t)z * 16384; coef = coef4 + (size_t)z * 1024;
        colsum = colsum4 + (size_t)z * 1024;
    } else {
        bid -= 16;
        int z = bid >> 4; qb = bid & 15; S = 4096; R = 64; accIdx = z;
        cmPart = cmPart3 + (size_t)z * 262144; coef = coef3 + (size_t)z * 4096;
        colsum = colsum3 + (size_t)z * 4096;
    }
    if (qb == 0 && threadIdx.x == 0) acc[accIdx] = 0.f;
    int q = qb * 256 + threadIdx.x;
    float m = cmPart[q];
    for (int r = 1; r < R; r++) m = fmaxf(m, cmPart[(size_t)r * S + q]);
    float c1 = 1.f / ((1.f - m) * 0.5f + MRF_EPS);
    coef[q] = make_float2((2.f - c1) * LOG2E, c1 * LOG2E);
    colsum[q] = 0.f;
}

// ================= colsum =================
__global__ __launch_bounds__(256) void colsum_all(
    const ushort_t* __restrict__ sim3, const float2* __restrict__ coef3, float* __restrict__ colsum3,
    const ushort_t* __restrict__ sim4, const float2* __restrict__ coef4, float* __restrict__ colsum4) {
    const ushort_t* sim; const float2* coef; float* colsum; int S, bx, by;
    int bid = blockIdx.x;
    if (bid < 256) {            // layer4: 4 z * (8 x 8)
        int z = bid >> 6, rem = bid & 63; by = rem >> 3; bx = rem & 7; S = 1024;
        sim = sim4 + (size_t)z * 1048576; coef = coef4 + (size_t)z * 1024;
        colsum = colsum4 + (size_t)z * 1024;
    } else {
        bid -= 256;
        int z = bid >> 10, rem = bid & 1023; by = rem >> 5; bx = rem & 31; S = 4096;
        sim = sim3 + (size_t)z * 16777216; coef = coef3 + (size_t)z * 4096;
        colsum = colsum3 + (size_t)z * 4096;
    }
    int tid = threadIdx.x, lane = tid & 63;
    int u = lane >> 4, lm = lane & 15;
    int sub = (tid >> 6) & 1, cg = tid >> 7;
    int nQB = S >> 7;
    int q = bx * 128 + cg * 64 + u * 16 + lm;
    float2 cc = coef[q];
    float c0 = cc.x, c1 = cc.y;
    const ushort_t* base = sim + ((size_t)(by * nQB + bx)) * 16384
                         + (size_t)((sub | (cg << 1)) * 4096 + u * 256 + lm * 4);
    float s = 0.f;
#pragma unroll
    for (int t = 0; t < 4; t++)
#pragma unroll
        for (int quad = 0; quad < 4; quad++) {
            ushort4_t w = *(const ushort4_t*)(base + t * 1024 + quad * 64);
            s += exp2f(c0 + c1 * bf2f(w.x)) + exp2f(c0 + c1 * bf2f(w.y))
               + exp2f(c0 + c1 * bf2f(w.z)) + exp2f(c0 + c1 * bf2f(w.w));
        }
    atomicAdd(colsum + q, s);
}

// ================= rowmax (inline fold: c0' = c0 - log2(colsum)) =================
__global__ __launch_bounds__(256) void rowmax_all(
    const ushort_t* __restrict__ sim3, const float2* __restrict__ coef3, const float* __restrict__ colsum3,
    const ushort_t* __restrict__ sim4, const float2* __restrict__ coef4, const float* __restrict__ colsum4,
    float* __restrict__ acc) {
    const ushort_t* sim; const float2* coef; const float* colsum;
    int S, blk; float* accSlot;
    int bid = blockIdx.x;
    if (bid < 1024) {           // layer3 first (4x q-scan per block)
        int z = bid >> 8; blk = bid & 255; S = 4096; accSlot = acc + z;
        sim = sim3 + (size_t)z * 16777216; coef = coef3 + (size_t)z * 4096;
        colsum = colsum3 + (size_t)z * 4096;
    } else {
        bid -= 1024;
        int z = bid >> 6; blk = bid & 63; S = 1024; accSlot = acc + 4 + z;
        sim = sim4 + (size_t)z * 1048576; coef = coef4 + (size_t)z * 1024;
        colsum = colsum4 + (size_t)z * 1024;
    }
    int wave = threadIdx.x >> 6, lane = threadIdx.x & 63;
    int g = blk * 4 + wave;
    int by = g >> 5, rem = g & 31;
    int sub = rem >> 4, t = (rem >> 2) & 3, quad = rem & 3;
    int u = lane >> 4, lm = lane & 15;
    int nQB = S >> 7;
    f32x4 m = {-INFINITY, -INFINITY, -INFINITY, -INFINITY};
    for (int bx = 0; bx < nQB; bx++) {
#pragma unroll
        for (int cg = 0; cg < 2; cg++) {
            int q = bx * 128 + cg * 64 + u * 16 + lm;
            float2 cc = coef[q];
            float c0p = cc.x - log2f(colsum[q]);
            const ushort_t* ptr = sim + ((size_t)(by * nQB + bx)) * 16384
                                + (size_t)((sub | (cg << 1)) * 4096 + (t * 4 + u) * 256 + quad * 64 + lm * 4);
            ushort4_t w = *(const ushort4_t*)ptr;
            m[0] = fmaxf(m[0], c0p + cc.y * bf2f(w.x));
            m[1] = fmaxf(m[1], c0p + cc.y * bf2f(w.y));
            m[2] = fmaxf(m[2], c0p + cc.y * bf2f(w.z));
            m[3] = fmaxf(m[3], c0p + cc.y * bf2f(w.w));
        }
    }
#pragma unroll
    for (int off = 32; off >= 1; off >>= 1)
#pragma unroll
        for (int e = 0; e < 4; e++)
            m[e] = fmaxf(m[e], __shfl_xor(m[e], off, 64));
    __shared__ float partial[4];
    if (lane == 0)
        partial[wave] = exp2f(m[0]) + exp2f(m[1]) + exp2f(m[2]) + exp2f(m[3]);
    __syncthreads();
    if (threadIdx.x == 0)
        atomicAdd(accSlot, partial[0] + partial[1] + partial[2] + partial[3]);
}

__global__ void finalize_kernel(const float* __restrict__ acc, float* __restrict__ out) {
    float loss = 0.f;
    for (int b = 0; b < 4; b++) loss += -logf(acc[b] * (1.f / 4096.f));
    for (int b = 0; b < 4; b++) loss += -2.f * logf(acc[4 + b] * (1.f / 1024.f));
    out[0] = loss;
}

extern "C" void kernel_launch(void* const* d_in, const int* in_sizes, int n_in,
                              void* d_out, int out_size, void* d_ws, size_t ws_size,
                              hipStream_t stream) {
    const float* gen3 = (const float*)d_in[0];
    const float* tar3 = (const float*)d_in[1];
    const float* gen4 = (const float*)d_in[2];
    const float* tar4 = (const float*)d_in[3];

    char* wsb = (char*)d_ws;
    size_t off = 0;
    auto alloc = [&](size_t bytes) {
        void* p = wsb + off;
        off += (bytes + 255) & ~(size_t)255;
        return p;
    };
    // layer3 (z=4): S=4096, C=256, R=64
    ushort_t* sim3 = (ushort_t*)alloc((size_t)4 * 16777216 * 2);   // 134.2 MB
    ushort_t* gnT3 = (ushort_t*)alloc((size_t)4 * 1048576 * 2);    // 8.4 MB
    ushort_t* tnT3 = (ushort_t*)alloc((size_t)4 * 1048576 * 2);    // 8.4 MB
    float* cmPart3 = (float*)alloc((size_t)4 * 262144 * 4);        // 4.2 MB
    float2* coef3 = (float2*)alloc((size_t)4 * 4096 * 8);
    float* colsum3 = (float*)alloc((size_t)4 * 4096 * 4);
    // layer4 (z=4): S=1024, C=512, R=16
    ushort_t* sim4 = (ushort_t*)alloc((size_t)4 * 1048576 * 2);    // 8.4 MB
    ushort_t* gnT4 = (ushort_t*)alloc((size_t)4 * 524288 * 2);     // 4.2 MB
    ushort_t* tnT4 = (ushort_t*)alloc((size_t)4 * 524288 * 2);     // 4.2 MB
    float* cmPart4 = (float*)alloc((size_t)4 * 16384 * 4);
    float2* coef4 = (float2*)alloc((size_t)4 * 1024 * 8);
    float* colsum4 = (float*)alloc((size_t)4 * 1024 * 4);
    float* acc = (float*)alloc(64 * 4);
    // total ~172 MB (ws is 256 MiB)

    prep_all<<<256 + 1024, 256, 0, stream>>>(
        gen3, tar3, gen4, tar4, gnT3, tnT3, gnT4, tnT4);
    gemm_all<<<256 + 4096, 256, 0, stream>>>(
        tnT3, gnT3, sim3, cmPart3, tnT4, gnT4, sim4, cmPart4);
    colmax_reduce_all<<<16 + 64, 256, 0, stream>>>(
        cmPart3, coef3, colsum3, cmPart4, coef4, colsum4, acc);
    colsum_all<<<256 + 4096, 256, 0, stream>>>(
        sim3, coef3, colsum3, sim4, coef4, colsum4);
    rowmax_all<<<1024 + 256, 256, 0, stream>>>(
        sim3, coef3, colsum3, sim4, coef4, colsum4, acc);
    finalize_kernel<<<1, 1, 0, stream>>>(acc, (float*)d_out);
}